// Round 5
// baseline (256.771 us; speedup 1.0000x reference)
//
#include <hip/hip_runtime.h>

// ---------------------------------------------------------------------------
// Attention block (B=2, S=2048, DIM=2048, H=32, KVH=8, HD=64, causal, RoPE)
// cvt(x)->bf16 ; transpose-cvt weights ; QKV GEMM (2-phase dbuf) ; RoPE ;
// V-transpose ; dual-q-tile flash attention (heavy+light tiles share the KV
// stream in ONE pass -> 2x ILP per wave) ; out GEMM -> fp32 d_out
// ---------------------------------------------------------------------------

using u16   = unsigned short;
using u32   = unsigned int;
using f32x4 = __attribute__((ext_vector_type(4))) float;
using f32x16= __attribute__((ext_vector_type(16))) float;
using s16x8 = __attribute__((ext_vector_type(8))) short;
using b16x8 = __attribute__((ext_vector_type(8))) __bf16;
using u16x4 = __attribute__((ext_vector_type(4))) unsigned short;
using u32x4 = __attribute__((ext_vector_type(4))) u32;

__device__ __forceinline__ u16 f2bf(float f) {
  u32 u = __builtin_bit_cast(u32, f);
  u = (u + 0x7fffu + ((u >> 16) & 1u)) >> 16;   // round-to-nearest-even
  return (u16)u;
}
__device__ __forceinline__ float bf2f(u32 lo16) {
  return __builtin_bit_cast(float, lo16 << 16);
}

__device__ __forceinline__ f32x4 mfma16(s16x8 a, s16x8 b, f32x4 c) {
  return __builtin_amdgcn_mfma_f32_16x16x32_bf16(
      __builtin_bit_cast(b16x8, a), __builtin_bit_cast(b16x8, b), c, 0, 0, 0);
}
__device__ __forceinline__ f32x16 mfma32(s16x8 a, s16x8 b, f32x16 c) {
  return __builtin_amdgcn_mfma_f32_32x32x16_bf16(
      __builtin_bit_cast(b16x8, a), __builtin_bit_cast(b16x8, b), c, 0, 0, 0);
}

__device__ __forceinline__ void gload_lds16(const void* g, void* l) {
  __builtin_amdgcn_global_load_lds(
      (const __attribute__((address_space(1))) void*)g,
      (__attribute__((address_space(3))) void*)l, 16, 0, 0);
}

__device__ __forceinline__ u32 cvtpk(float lo, float hi) {
  u32 r; asm("v_cvt_pk_bf16_f32 %0, %1, %2" : "=v"(r) : "v"(lo), "v"(hi));
  return r;
}

__device__ __forceinline__ float fexp2(float x) {
#if __has_builtin(__builtin_amdgcn_exp2f)
  return __builtin_amdgcn_exp2f(x);
#else
  return exp2f(x);
#endif
}

// ---------------------------------------------------------------------------
__global__ __launch_bounds__(256) void cvt_kernel(const float* __restrict__ src,
                                                  u16* __restrict__ dst, int n4) {
  int i = blockIdx.x * 256 + threadIdx.x;
  if (i >= n4) return;
  f32x4 v = *(const f32x4*)(src + (size_t)i * 4);
  u16x4 r;
#pragma unroll
  for (int j = 0; j < 4; ++j) r[j] = f2bf(v[j]);
  *(u16x4*)(dst + (size_t)i * 4) = r;
}

// ---------------------------------------------------------------------------
__global__ __launch_bounds__(256) void tcvt_kernel(const float* __restrict__ src,
                                                   u16* __restrict__ dst, int N) {
  __shared__ float t[32][33];
  const int n0 = blockIdx.x * 32, k0 = blockIdx.y * 32;
  const int tx = threadIdx.x & 31, ty = threadIdx.x >> 5;
#pragma unroll
  for (int r = 0; r < 4; ++r)
    t[ty + 8 * r][tx] = src[(size_t)(k0 + ty + 8 * r) * N + n0 + tx];
  __syncthreads();
#pragma unroll
  for (int r = 0; r < 4; ++r)
    dst[(size_t)(n0 + ty + 8 * r) * 2048 + k0 + tx] = f2bf(t[tx][ty + 8 * r]);
}

// ---------------------------------------------------------------------------
__global__ __launch_bounds__(256) void rope_kernel(u16* __restrict__ qkv,
                                                   const float* __restrict__ cs,
                                                   const float* __restrict__ sn) {
  const int m = blockIdx.x;
  const int p = blockIdx.y * 256 + threadIdx.x;  // 0..1279
  const int s = m & 2047;
  int col, d2;
  if (p < 1024) { col = 2 * p; d2 = p & 31; }
  else { int pk = p - 1024; col = 2048 + 2 * pk; d2 = pk & 31; }
  const float c = cs[s * 32 + d2], si = sn[s * 32 + d2];
  u32* addr = (u32*)&qkv[(size_t)m * 3072 + col];
  u32 v = *addr;
  float a = bf2f(v & 0xffffu), b = bf2f(v >> 16);
  float na = a * c - b * si;
  float nb = a * si + b * c;
  *addr = (u32)f2bf(na) | ((u32)f2bf(nb) << 16);
}

// ---------------------------------------------------------------------------
// V transpose: qkv v-section -> VtG[(b*8+kvh)*64 + d][s]  ([16*64][2048] bf16)
__global__ __launch_bounds__(256) void vt_kernel(const u16* __restrict__ qkv,
                                                 u16* __restrict__ VtG) {
  __shared__ u16 t[64][65];
  const int s0 = blockIdx.x * 64;
  const int bk = blockIdx.y;            // b*8 + kvh
  const int b = bk >> 3, kvh = bk & 7;
  const int tx = threadIdx.x & 63, ty = threadIdx.x >> 6;  // ty 0..3
#pragma unroll
  for (int r = 0; r < 16; ++r)
    t[ty + 4 * r][tx] =
        qkv[(size_t)(b * 2048 + s0 + ty + 4 * r) * 3072 + 2560 + kvh * 64 + tx];
  __syncthreads();
#pragma unroll
  for (int r = 0; r < 16; ++r)
    VtG[(size_t)(bk * 64 + ty + 4 * r) * 2048 + s0 + tx] = t[tx][ty + 4 * r];
}

// ---------------------------------------------------------------------------
// GEMM: C[M,N] = A[M,K]*Bt[N,K]^T. 128x128 tile, BK=32, 2-phase double buffer,
// XCD-bijective swizzle. 1D grid (must be %8==0), GX = N/128.
template <bool BF16OUT>
__global__ __launch_bounds__(256) void gemm_bt(const u16* __restrict__ A,
                                               const u16* __restrict__ Bt,
                                               void* __restrict__ Cv,
                                               int M, int N, int K, int GX) {
  __shared__ u16 As[2][128 * 32];
  __shared__ u16 Bs[2][128 * 32];
  const int tid = threadIdx.x;
  const int wid = tid >> 6, lane = tid & 63;
  const int l15 = lane & 15, lq = lane >> 4;
  const int wr = wid >> 1, wc = wid & 1;
  const int cpx = gridDim.x >> 3;                 // gridDim.x % 8 == 0
  const int swz = (blockIdx.x & 7) * cpx + (blockIdx.x >> 3);
  const int m0 = (swz / GX) * 128, n0 = (swz % GX) * 128;

  const int srow16 = lane >> 2;
  const int k8 = (lane & 3) * 8;

  auto STAGE = [&](int bb, int kt) {
#pragma unroll
    for (int i = 0; i < 2; ++i) {
      const int r = wid * 2 + i;                  // 16-row region
      const int row = r * 16 + srow16;
      gload_lds16(A + (size_t)(m0 + row) * K + kt + k8, &As[bb][r * 512]);
      gload_lds16(Bt + (size_t)(n0 + row) * K + kt + k8, &Bs[bb][r * 512]);
    }
  };

  f32x4 acc[4][4] = {};
  STAGE(0, 0);
  __syncthreads();
  int cur = 0;
  for (int kt = 0; kt < K; kt += 32) {
    if (kt + 32 < K) STAGE(cur ^ 1, kt + 32);
    s16x8 af[4], bf[4];
#pragma unroll
    for (int i = 0; i < 4; ++i)
      af[i] = *(const s16x8*)&As[cur][(wr * 64 + i * 16 + l15) * 32 + 8 * lq];
#pragma unroll
    for (int j = 0; j < 4; ++j)
      bf[j] = *(const s16x8*)&Bs[cur][(wc * 64 + j * 16 + l15) * 32 + 8 * lq];
#pragma unroll
    for (int i = 0; i < 4; ++i)
#pragma unroll
      for (int j = 0; j < 4; ++j)
        acc[i][j] = mfma16(af[i], bf[j], acc[i][j]);
    __syncthreads();                              // drains next-tile loads too
    cur ^= 1;
  }

  u16* Cb = (u16*)Cv;
  float* Cf = (float*)Cv;
#pragma unroll
  for (int i = 0; i < 4; ++i)
#pragma unroll
    for (int j = 0; j < 4; ++j)
#pragma unroll
      for (int r = 0; r < 4; ++r) {
        const int row = m0 + wr * 64 + i * 16 + 4 * lq + r;
        const int col = n0 + wc * 64 + j * 16 + l15;
        if constexpr (BF16OUT) Cb[(size_t)row * N + col] = f2bf(acc[i][j][r]);
        else                   Cf[(size_t)row * N + col] = acc[i][j][r];
      }
}

// ---------------------------------------------------------------------------
// Flash attention, dual-q-tile: block bx owns q-tiles {15-bx (heavy), bx
// (light)}; ONE pass over the heavy tile's KV range, light tile active for
// its prefix and sharing the staged K/V tile -> 2x independent chains per
// wave where both are active. 4 waves x 32 q-rows, KVBLK=64, 4-deep LDS ring
// with 2-ahead counted-vmcnt prefetch. Swapped QK^T + O^T (lane-local
// softmax), defer-max THR=8, tree reductions.
__global__ __launch_bounds__(256) void attn_kernel(const u16* __restrict__ qkv,
                                                   const u16* __restrict__ VtG,
                                                   u16* __restrict__ aout) {
  constexpr int QSTR = 3072;
  constexpr float SCL = 0.18033688011112042f;    // (1/8) * log2(e)
  const int bx = blockIdx.x;                     // 0..7
  const int bh = blockIdx.y;
  const int b = bh >> 5, h = bh & 31, kvh = h >> 2;
  const int tid = threadIdx.x, w = tid >> 6;     // wave 0..3
  const int l31 = tid & 31, hh = (tid >> 5) & 1;

  __shared__ u16 Ks[4][64 * 64];
  __shared__ u16 Vs[4][64 * 64];

  // staging: thread covers rows (tid>>3), (tid>>3)+32; 16B slot tid&7
  const int srow = tid >> 3, sslot = tid & 7;
  const int sd8 = (sslot ^ (srow & 7)) * 8;      // pre-swizzled source slot
  const u16* kg = qkv + (size_t)(b * 2048 + srow) * QSTR + 2048 + kvh * 64 + sd8;
  const u16* vg = VtG + (size_t)((b * 8 + kvh) * 64 + srow) * 2048 + sd8;
  const int xsw = l31 & 7;                       // read-side row XOR

  auto STAGE = [&](int bb, int t) {
    const size_t ko = (size_t)t * 64 * QSTR;
    const size_t vo = (size_t)t * 64;
    gload_lds16(kg + ko, &Ks[bb][w * 512]);
    gload_lds16(kg + ko + (size_t)32 * QSTR, &Ks[bb][2048 + w * 512]);
    gload_lds16(vg + vo, &Vs[bb][w * 512]);
    gload_lds16(vg + vo + (size_t)32 * 2048, &Vs[bb][2048 + w * 512]);
  };

  const int qh = 15 - bx, ql = bx;
  const int qah = qh * 128 + w * 32 + l31;       // heavy lane q-row
  const int qal = ql * 128 + w * 32 + l31;       // light lane q-row

  const u16* qrh = qkv + (size_t)(b * 2048 + qah) * QSTR + h * 64;
  const u16* qrl = qkv + (size_t)(b * 2048 + qal) * QSTR + h * 64;
  s16x8 qfh[4], qfl[4];
#pragma unroll
  for (int s = 0; s < 4; ++s) {
    qfh[s] = *(const s16x8*)(qrh + 16 * s + 8 * hh);
    qfl[s] = *(const s16x8*)(qrl + 16 * s + 8 * hh);
  }

  f32x16 oh0 = {}, oh1 = {}, ol0 = {}, ol1 = {};
  float mh = 0.f, lh = 0.f, ml = 0.f, ll = 0.f;

  // per-tile compute: QK^T -> masked online softmax -> pack -> PV
  auto tile_compute = [&](const u16* Kb, const u16* Vb, int kv0, int qt,
                          int q_abs, const s16x8* qf, f32x16& o0, f32x16& o1,
                          float& mrun, float& lrun) {
    f32x16 a0 = {}, a1 = {};
    __builtin_amdgcn_s_setprio(1);
#pragma unroll
    for (int s = 0; s < 4; ++s) {
      const int c0 = ((2 * s + hh) ^ xsw) * 8;
      s16x8 k0 = *(const s16x8*)(Kb + l31 * 64 + c0);
      s16x8 k1 = *(const s16x8*)(Kb + (32 + l31) * 64 + c0);
      a0 = mfma32(k0, qf[s], a0);
      a1 = mfma32(k1, qf[s], a1);
    }
    __builtin_amdgcn_s_setprio(0);

    if (kv0 + 63 > qt * 128 + w * 32) {          // diagonal tile: causal mask
#pragma unroll
      for (int r = 0; r < 16; ++r) {
        const int kva = kv0 + (r & 3) + 8 * (r >> 2) + 4 * hh;
        if (kva > q_abs) a0[r] = -3e38f;
        if (kva + 32 > q_abs) a1[r] = -3e38f;
      }
    }

    // tree max (depth 5 instead of 32-deep chain)
    float mr[16];
#pragma unroll
    for (int r = 0; r < 16; ++r) mr[r] = fmaxf(a0[r], a1[r]);
#pragma unroll
    for (int s2 = 8; s2 >= 1; s2 >>= 1)
#pragma unroll
      for (int r = 0; r < s2; ++r) mr[r] = fmaxf(mr[r], mr[r + s2]);
    const float mxs = mr[0] * SCL;
    const float mx = fmaxf(mxs, __shfl_xor(mxs, 32));
    if (__any(mx > mrun + 8.f)) {                // defer-max
      const float mnew = fmaxf(mrun, mx);
      const float c1 = fexp2(mrun - mnew);
      mrun = mnew;
      lrun *= c1;
#pragma unroll
      for (int r = 0; r < 16; ++r) { o0[r] *= c1; o1[r] *= c1; }
    }

#pragma unroll
    for (int r = 0; r < 16; ++r) {
      a0[r] = fexp2(__builtin_fmaf(a0[r], SCL, -mrun));
      a1[r] = fexp2(__builtin_fmaf(a1[r], SCL, -mrun));
    }
    // tree sum
    float sr[16];
#pragma unroll
    for (int r = 0; r < 16; ++r) sr[r] = a0[r] + a1[r];
#pragma unroll
    for (int s2 = 8; s2 >= 1; s2 >>= 1)
#pragma unroll
      for (int r = 0; r < s2; ++r) sr[r] += sr[r + s2];
    lrun += sr[0] + __shfl_xor(sr[0], 32);

    // pack P^T B-fragments (cvt_pk + permlane32_swap)
    s16x8 pf[4];
#pragma unroll
    for (int s = 0; s < 4; ++s) {
      const f32x16& ps = (s & 2) ? a1 : a0;
      const int g4 = (s & 1) * 8;
      u32 x  = cvtpk(ps[g4 + 0], ps[g4 + 1]);
      u32 x2 = cvtpk(ps[g4 + 2], ps[g4 + 3]);
      u32 y  = cvtpk(ps[g4 + 4], ps[g4 + 5]);
      u32 y2 = cvtpk(ps[g4 + 6], ps[g4 + 7]);
      asm("v_permlane32_swap_b32 %0, %1" : "+v"(x), "+v"(y));
      asm("v_permlane32_swap_b32 %0, %1" : "+v"(x2), "+v"(y2));
      u32x4 fr = {x, x2, y, y2};
      pf[s] = __builtin_bit_cast(s16x8, fr);
    }

    // PV: O^T += V^T * P^T
    __builtin_amdgcn_s_setprio(1);
#pragma unroll
    for (int s = 0; s < 4; ++s) {
      const int c0 = ((2 * s + hh) ^ xsw) * 8;
      s16x8 v0f = *(const s16x8*)(Vb + l31 * 64 + c0);
      s16x8 v1f = *(const s16x8*)(Vb + (32 + l31) * 64 + c0);
      o0 = mfma32(v0f, pf[s], o0);
      o1 = mfma32(v1f, pf[s], o1);
    }
    __builtin_amdgcn_s_setprio(0);
  };

  const int nth = 2 * qh + 2;                    // heavy tile count (>= 18)
  STAGE(0, 0);
  STAGE(1, 1);

  for (int t = 0; t < nth; ++t) {
    if (t + 2 < nth) {
      STAGE((t + 2) & 3, t + 2);
      asm volatile("s_waitcnt vmcnt(8)" ::: "memory");
    } else if (t + 2 == nth) {
      asm volatile("s_waitcnt vmcnt(4)" ::: "memory");
    } else {
      asm volatile("s_waitcnt vmcnt(0)" ::: "memory");
    }
    __builtin_amdgcn_s_barrier();                // all waves' tile-t stage done

    const int kv0 = t * 64;
    const u16* Kb = &Ks[t & 3][0];
    const u16* Vb = &Vs[t & 3][0];
    if (kv0 <= qh * 128 + w * 32 + 31)
      tile_compute(Kb, Vb, kv0, qh, qah, qfh, oh0, oh1, mh, lh);
    if (kv0 <= ql * 128 + w * 32 + 31)
      tile_compute(Kb, Vb, kv0, ql, qal, qfl, ol0, ol1, ml, ll);
  }

  const float invh = 1.f / lh, invl = 1.f / ll;
  u16* obh = aout + (size_t)(b * 2048 + qah) * 2048 + h * 64;
  u16* obl = aout + (size_t)(b * 2048 + qal) * 2048 + h * 64;
#pragma unroll
  for (int g = 0; g < 4; ++g) {
    u16x4 w0, w1, w2, w3;
#pragma unroll
    for (int j = 0; j < 4; ++j) {
      w0[j] = f2bf(oh0[4 * g + j] * invh);
      w1[j] = f2bf(oh1[4 * g + j] * invh);
      w2[j] = f2bf(ol0[4 * g + j] * invl);
      w3[j] = f2bf(ol1[4 * g + j] * invl);
    }
    *(u16x4*)(obh + 8 * g + 4 * hh) = w0;
    *(u16x4*)(obh + 32 + 8 * g + 4 * hh) = w1;
    *(u16x4*)(obl + 8 * g + 4 * hh) = w2;
    *(u16x4*)(obl + 32 + 8 * g + 4 * hh) = w3;
  }
}

// ---------------------------------------------------------------------------
extern "C" void kernel_launch(void* const* d_in, const int* in_sizes, int n_in,
                              void* d_out, int out_size, void* d_ws, size_t ws_size,
                              hipStream_t stream) {
  const float* x    = (const float*)d_in[0];
  const float* wq   = (const float*)d_in[1];
  const float* wk   = (const float*)d_in[2];
  const float* wv   = (const float*)d_in[3];
  const float* wo   = (const float*)d_in[4];
  const float* cosT = (const float*)d_in[5];
  const float* sinT = (const float*)d_in[6];
  float* out = (float*)d_out;

  const size_t SZ_XB   = (size_t)4096 * 2048 * 2;
  const size_t SZ_WQKV = (size_t)3072 * 2048 * 2;
  const size_t SZ_WO   = (size_t)2048 * 2048 * 2;
  const size_t SZ_QKV  = (size_t)4096 * 3072 * 2;
  const size_t SZ_ATT  = (size_t)4096 * 2048 * 2;
  if (ws_size < SZ_XB + SZ_WQKV + SZ_WO + SZ_QKV + SZ_ATT) return;

  char* p = (char*)d_ws;
  u16* xb    = (u16*)p; p += SZ_XB;
  u16* wqkvT = (u16*)p; p += SZ_WQKV;
  u16* woT   = (u16*)p; p += SZ_WO;
  u16* qkv   = (u16*)p; p += SZ_QKV;
  u16* attn  = (u16*)p; p += SZ_ATT;
  u16* VtG   = xb;   // xb is dead after the QKV GEMM; vt_kernel runs after it

  cvt_kernel<<<8192, 256, 0, stream>>>(x, xb, 2097152);
  tcvt_kernel<<<dim3(64, 64), 256, 0, stream>>>(wq, wqkvT, 2048);
  tcvt_kernel<<<dim3(16, 64), 256, 0, stream>>>(wk, wqkvT + (size_t)2048 * 2048, 512);
  tcvt_kernel<<<dim3(16, 64), 256, 0, stream>>>(wv, wqkvT + (size_t)2560 * 2048, 512);
  tcvt_kernel<<<dim3(64, 64), 256, 0, stream>>>(wo, woT, 2048);

  gemm_bt<true><<<768, 256, 0, stream>>>(xb, wqkvT, qkv, 4096, 3072, 2048, 24);
  rope_kernel<<<dim3(4096, 5), 256, 0, stream>>>(qkv, cosT, sinT);
  vt_kernel<<<dim3(32, 16), 256, 0, stream>>>(qkv, VtG);
  attn_kernel<<<dim3(8, 64), 256, 0, stream>>>(qkv, VtG, attn);
  gemm_bt<false><<<512, 256, 0, stream>>>(attn, woT, out, 4096, 2048, 2048, 16);
}

// Round 6
// 240.320 us; speedup vs baseline: 1.0685x; 1.0685x over previous
//
#include <hip/hip_runtime.h>

// ---------------------------------------------------------------------------
// Attention block (B=2, S=2048, DIM=2048, H=32, KVH=8, HD=64, causal, RoPE)
// cvt(x)->bf16 ; transpose-cvt weights ; QKV GEMM (256^2 8-wave phased) ;
// RoPE ; V-transpose ; balanced paired-q-tile flash attention (round-4) ;
// out GEMM (128^2 2-phase) -> fp32 d_out
// ---------------------------------------------------------------------------

using u16   = unsigned short;
using u32   = unsigned int;
using f32x4 = __attribute__((ext_vector_type(4))) float;
using f32x16= __attribute__((ext_vector_type(16))) float;
using s16x8 = __attribute__((ext_vector_type(8))) short;
using b16x8 = __attribute__((ext_vector_type(8))) __bf16;
using u16x4 = __attribute__((ext_vector_type(4))) unsigned short;
using u32x4 = __attribute__((ext_vector_type(4))) u32;

__device__ __forceinline__ u16 f2bf(float f) {
  u32 u = __builtin_bit_cast(u32, f);
  u = (u + 0x7fffu + ((u >> 16) & 1u)) >> 16;   // round-to-nearest-even
  return (u16)u;
}
__device__ __forceinline__ float bf2f(u32 lo16) {
  return __builtin_bit_cast(float, lo16 << 16);
}

__device__ __forceinline__ f32x4 mfma16(s16x8 a, s16x8 b, f32x4 c) {
  return __builtin_amdgcn_mfma_f32_16x16x32_bf16(
      __builtin_bit_cast(b16x8, a), __builtin_bit_cast(b16x8, b), c, 0, 0, 0);
}
__device__ __forceinline__ f32x16 mfma32(s16x8 a, s16x8 b, f32x16 c) {
  return __builtin_amdgcn_mfma_f32_32x32x16_bf16(
      __builtin_bit_cast(b16x8, a), __builtin_bit_cast(b16x8, b), c, 0, 0, 0);
}

__device__ __forceinline__ void gload_lds16(const void* g, void* l) {
  __builtin_amdgcn_global_load_lds(
      (const __attribute__((address_space(1))) void*)g,
      (__attribute__((address_space(3))) void*)l, 16, 0, 0);
}

__device__ __forceinline__ u32 cvtpk(float lo, float hi) {
  u32 r; asm("v_cvt_pk_bf16_f32 %0, %1, %2" : "=v"(r) : "v"(lo), "v"(hi));
  return r;
}

__device__ __forceinline__ float fexp2(float x) {
#if __has_builtin(__builtin_amdgcn_exp2f)
  return __builtin_amdgcn_exp2f(x);
#else
  return exp2f(x);
#endif
}

// ---------------------------------------------------------------------------
__global__ __launch_bounds__(256) void cvt_kernel(const float* __restrict__ src,
                                                  u16* __restrict__ dst, int n4) {
  int i = blockIdx.x * 256 + threadIdx.x;
  if (i >= n4) return;
  f32x4 v = *(const f32x4*)(src + (size_t)i * 4);
  u16x4 r;
#pragma unroll
  for (int j = 0; j < 4; ++j) r[j] = f2bf(v[j]);
  *(u16x4*)(dst + (size_t)i * 4) = r;
}

// ---------------------------------------------------------------------------
__global__ __launch_bounds__(256) void tcvt_kernel(const float* __restrict__ src,
                                                   u16* __restrict__ dst, int N) {
  __shared__ float t[32][33];
  const int n0 = blockIdx.x * 32, k0 = blockIdx.y * 32;
  const int tx = threadIdx.x & 31, ty = threadIdx.x >> 5;
#pragma unroll
  for (int r = 0; r < 4; ++r)
    t[ty + 8 * r][tx] = src[(size_t)(k0 + ty + 8 * r) * N + n0 + tx];
  __syncthreads();
#pragma unroll
  for (int r = 0; r < 4; ++r)
    dst[(size_t)(n0 + ty + 8 * r) * 2048 + k0 + tx] = f2bf(t[tx][ty + 8 * r]);
}

// ---------------------------------------------------------------------------
__global__ __launch_bounds__(256) void rope_kernel(u16* __restrict__ qkv,
                                                   const float* __restrict__ cs,
                                                   const float* __restrict__ sn) {
  const int m = blockIdx.x;
  const int p = blockIdx.y * 256 + threadIdx.x;  // 0..1279
  const int s = m & 2047;
  int col, d2;
  if (p < 1024) { col = 2 * p; d2 = p & 31; }
  else { int pk = p - 1024; col = 2048 + 2 * pk; d2 = pk & 31; }
  const float c = cs[s * 32 + d2], si = sn[s * 32 + d2];
  u32* addr = (u32*)&qkv[(size_t)m * 3072 + col];
  u32 v = *addr;
  float a = bf2f(v & 0xffffu), b = bf2f(v >> 16);
  float na = a * c - b * si;
  float nb = a * si + b * c;
  *addr = (u32)f2bf(na) | ((u32)f2bf(nb) << 16);
}

// ---------------------------------------------------------------------------
// V transpose: qkv v-section -> VtG[(b*8+kvh)*64 + d][s]  ([16*64][2048] bf16)
__global__ __launch_bounds__(256) void vt_kernel(const u16* __restrict__ qkv,
                                                 u16* __restrict__ VtG) {
  __shared__ u16 t[64][65];
  const int s0 = blockIdx.x * 64;
  const int bk = blockIdx.y;            // b*8 + kvh
  const int b = bk >> 3, kvh = bk & 7;
  const int tx = threadIdx.x & 63, ty = threadIdx.x >> 6;  // ty 0..3
#pragma unroll
  for (int r = 0; r < 16; ++r)
    t[ty + 4 * r][tx] =
        qkv[(size_t)(b * 2048 + s0 + ty + 4 * r) * 3072 + 2560 + kvh * 64 + tx];
  __syncthreads();
#pragma unroll
  for (int r = 0; r < 16; ++r)
    VtG[(size_t)(bk * 64 + ty + 4 * r) * 2048 + s0 + tx] = t[tx][ty + 4 * r];
}

// ---------------------------------------------------------------------------
// 256x256 BK=64 8-wave phased GEMM (bf16 out): C[M,N] = A[M,K] * Bt[N,K]^T.
// Frag-major LDS: cell (frag,ks,lane) holds the 8 bf16 lane `lane` consumes
// for that 16x16x32 fragment -> ds_read_b128 at lane*16B, conflict-free.
// Staging pre-permutes the GLOBAL source address; LDS writes stay linear.
// 4 phases/K-tile; stage issued 4 phases ahead; __syncthreads at boundary.
__global__ __launch_bounds__(512, 2) void gemm256(const u16* __restrict__ A,
                                                  const u16* __restrict__ Bt,
                                                  u16* __restrict__ C,
                                                  int M, int N, int K, int GX) {
  __shared__ u16 As[2][16 * 2 * 512];   // [buf][frag*2+ks][lane*8], 32 KB/buf
  __shared__ u16 Bs[2][16 * 2 * 512];
  const int tid = threadIdx.x;
  const int wv = tid >> 6, lane = tid & 63;
  const int l15 = lane & 15, lq = lane >> 4;
  const int wm = wv >> 2, wn = wv & 3;            // 2 x 4 wave grid
  const int cpx = gridDim.x >> 3;                 // grid % 8 == 0
  const int swz = (blockIdx.x & 7) * cpx + (blockIdx.x >> 3);
  const int m0 = (swz / GX) * 256, n0 = (swz % GX) * 256;

  // staging source per lane: row f*16+(lane&15), k = ks*32 + 8*(lane>>4)
  const int sr = lane & 15, sk = 8 * (lane >> 4);

  auto STAGE = [&](int bb, int kt) {
#pragma unroll
    for (int i = 0; i < 4; ++i) {
      const int fk = wv * 4 + i;                  // 0..31 = frag*2+ks
      const int f = fk >> 1, ks = fk & 1;
      const size_t gro = (size_t)(f * 16 + sr);
      const int gk = kt + ks * 32 + sk;
      gload_lds16(A + (m0 + gro) * K + gk, &As[bb][fk * 512]);
      gload_lds16(Bt + (n0 + gro) * K + gk, &Bs[bb][fk * 512]);
    }
  };

  f32x4 acc[8][4] = {};
  STAGE(0, 0);
  __syncthreads();
  int c = 0;

  for (int kt = 0; kt < K; kt += 64) {
    s16x8 a4[4], b4[4];
    // ---- phase 0: ks0, m-frags 0-3 (+ stage next tile)
#pragma unroll
    for (int i = 0; i < 4; ++i)
      a4[i] = *(const s16x8*)&As[c][((wm * 8 + i) * 2 + 0) * 512 + lane * 8];
#pragma unroll
    for (int j = 0; j < 4; ++j)
      b4[j] = *(const s16x8*)&Bs[c][((wn * 4 + j) * 2 + 0) * 512 + lane * 8];
    if (kt + 64 < K) STAGE(c ^ 1, kt + 64);
    __builtin_amdgcn_s_setprio(1);
#pragma unroll
    for (int i = 0; i < 4; ++i)
#pragma unroll
      for (int j = 0; j < 4; ++j) acc[i][j] = mfma16(a4[i], b4[j], acc[i][j]);
    __builtin_amdgcn_s_setprio(0);
    __builtin_amdgcn_s_barrier();
    // ---- phase 1: ks0, m-frags 4-7 (b4 reused)
#pragma unroll
    for (int i = 0; i < 4; ++i)
      a4[i] = *(const s16x8*)&As[c][((wm * 8 + 4 + i) * 2 + 0) * 512 + lane * 8];
    __builtin_amdgcn_s_setprio(1);
#pragma unroll
    for (int i = 0; i < 4; ++i)
#pragma unroll
      for (int j = 0; j < 4; ++j)
        acc[4 + i][j] = mfma16(a4[i], b4[j], acc[4 + i][j]);
    __builtin_amdgcn_s_setprio(0);
    __builtin_amdgcn_s_barrier();
    // ---- phase 2: ks1, m-frags 0-3
#pragma unroll
    for (int i = 0; i < 4; ++i)
      a4[i] = *(const s16x8*)&As[c][((wm * 8 + i) * 2 + 1) * 512 + lane * 8];
#pragma unroll
    for (int j = 0; j < 4; ++j)
      b4[j] = *(const s16x8*)&Bs[c][((wn * 4 + j) * 2 + 1) * 512 + lane * 8];
    __builtin_amdgcn_s_setprio(1);
#pragma unroll
    for (int i = 0; i < 4; ++i)
#pragma unroll
      for (int j = 0; j < 4; ++j) acc[i][j] = mfma16(a4[i], b4[j], acc[i][j]);
    __builtin_amdgcn_s_setprio(0);
    __builtin_amdgcn_s_barrier();
    // ---- phase 3: ks1, m-frags 4-7
#pragma unroll
    for (int i = 0; i < 4; ++i)
      a4[i] = *(const s16x8*)&As[c][((wm * 8 + 4 + i) * 2 + 1) * 512 + lane * 8];
    __builtin_amdgcn_s_setprio(1);
#pragma unroll
    for (int i = 0; i < 4; ++i)
#pragma unroll
      for (int j = 0; j < 4; ++j)
        acc[4 + i][j] = mfma16(a4[i], b4[j], acc[4 + i][j]);
    __builtin_amdgcn_s_setprio(0);
    // ---- tile boundary: full sync (drains vmcnt for next tile's stage,
    // which was issued 4 phases ago; protects buffer swap)
    __syncthreads();
    c ^= 1;
  }

#pragma unroll
  for (int i = 0; i < 8; ++i)
#pragma unroll
    for (int j = 0; j < 4; ++j)
#pragma unroll
      for (int r = 0; r < 4; ++r) {
        const int row = m0 + wm * 128 + i * 16 + 4 * lq + r;
        const int col = n0 + wn * 64 + j * 16 + l15;
        C[(size_t)row * N + col] = f2bf(acc[i][j][r]);
      }
}

// ---------------------------------------------------------------------------
// 128x128 BK=32 2-phase GEMM (fp32 out) for the output projection.
template <bool BF16OUT>
__global__ __launch_bounds__(256) void gemm_bt(const u16* __restrict__ A,
                                               const u16* __restrict__ Bt,
                                               void* __restrict__ Cv,
                                               int M, int N, int K, int GX) {
  __shared__ u16 As[2][128 * 32];
  __shared__ u16 Bs[2][128 * 32];
  const int tid = threadIdx.x;
  const int wid = tid >> 6, lane = tid & 63;
  const int l15 = lane & 15, lq = lane >> 4;
  const int wr = wid >> 1, wc = wid & 1;
  const int cpx = gridDim.x >> 3;                 // gridDim.x % 8 == 0
  const int swz = (blockIdx.x & 7) * cpx + (blockIdx.x >> 3);
  const int m0 = (swz / GX) * 128, n0 = (swz % GX) * 128;

  const int srow16 = lane >> 2;
  const int k8 = (lane & 3) * 8;

  auto STAGE = [&](int bb, int kt) {
#pragma unroll
    for (int i = 0; i < 2; ++i) {
      const int r = wid * 2 + i;                  // 16-row region
      const int row = r * 16 + srow16;
      gload_lds16(A + (size_t)(m0 + row) * K + kt + k8, &As[bb][r * 512]);
      gload_lds16(Bt + (size_t)(n0 + row) * K + kt + k8, &Bs[bb][r * 512]);
    }
  };

  f32x4 acc[4][4] = {};
  STAGE(0, 0);
  __syncthreads();
  int cur = 0;
  for (int kt = 0; kt < K; kt += 32) {
    if (kt + 32 < K) STAGE(cur ^ 1, kt + 32);
    s16x8 af[4], bf[4];
#pragma unroll
    for (int i = 0; i < 4; ++i)
      af[i] = *(const s16x8*)&As[cur][(wr * 64 + i * 16 + l15) * 32 + 8 * lq];
#pragma unroll
    for (int j = 0; j < 4; ++j)
      bf[j] = *(const s16x8*)&Bs[cur][(wc * 64 + j * 16 + l15) * 32 + 8 * lq];
#pragma unroll
    for (int i = 0; i < 4; ++i)
#pragma unroll
      for (int j = 0; j < 4; ++j)
        acc[i][j] = mfma16(af[i], bf[j], acc[i][j]);
    __syncthreads();                              // drains next-tile loads too
    cur ^= 1;
  }

  u16* Cb = (u16*)Cv;
  float* Cf = (float*)Cv;
#pragma unroll
  for (int i = 0; i < 4; ++i)
#pragma unroll
    for (int j = 0; j < 4; ++j)
#pragma unroll
      for (int r = 0; r < 4; ++r) {
        const int row = m0 + wr * 64 + i * 16 + 4 * lq + r;
        const int col = n0 + wc * 64 + j * 16 + l15;
        if constexpr (BF16OUT) Cb[(size_t)row * N + col] = f2bf(acc[i][j][r]);
        else                   Cf[(size_t)row * N + col] = acc[i][j][r];
      }
}

// ---------------------------------------------------------------------------
// Flash attention (round-4 version): balanced pairs + 4-deep LDS ring with
// counted-vmcnt prefetch (2 tiles ahead). 4 waves x 32 q-rows (QBLK=128),
// KVBLK=64. Block bx does q-tiles {15-bx, bx} -> constant 34 KV-tiles/block.
// Swapped QK^T (S^T) + O^T: softmax lane-local. Defer-max THR=8 (log2).
__global__ __launch_bounds__(256) void attn_kernel(const u16* __restrict__ qkv,
                                                   const u16* __restrict__ VtG,
                                                   u16* __restrict__ aout) {
  constexpr int QSTR = 3072;
  constexpr float SCL = 0.18033688011112042f;    // (1/8) * log2(e)
  const int bx = blockIdx.x;                     // 0..7
  const int bh = blockIdx.y;
  const int b = bh >> 5, h = bh & 31, kvh = h >> 2;
  const int tid = threadIdx.x, w = tid >> 6;     // wave 0..3
  const int l31 = tid & 31, hh = (tid >> 5) & 1;

  __shared__ u16 Ks[4][64 * 64];
  __shared__ u16 Vs[4][64 * 64];

  const int srow = tid >> 3, sslot = tid & 7;
  const int sd8 = (sslot ^ (srow & 7)) * 8;      // pre-swizzled source slot
  const u16* kg = qkv + (size_t)(b * 2048 + srow) * QSTR + 2048 + kvh * 64 + sd8;
  const u16* vg = VtG + (size_t)((b * 8 + kvh) * 64 + srow) * 2048 + sd8;
  const int xsw = l31 & 7;                       // read-side row XOR

  auto STAGE = [&](int bb, int t) {
    const size_t ko = (size_t)t * 64 * QSTR;
    const size_t vo = (size_t)t * 64;
    gload_lds16(kg + ko, &Ks[bb][w * 512]);
    gload_lds16(kg + ko + (size_t)32 * QSTR, &Ks[bb][2048 + w * 512]);
    gload_lds16(vg + vo, &Vs[bb][w * 512]);
    gload_lds16(vg + vo + (size_t)32 * 2048, &Vs[bb][2048 + w * 512]);
  };

  auto process = [&](int qt) {
    const int q_abs = qt * 128 + w * 32 + l31;   // this lane's q row
    const u16* qrow = qkv + (size_t)(b * 2048 + q_abs) * QSTR + h * 64;
    s16x8 qf[4];
#pragma unroll
    for (int s = 0; s < 4; ++s) qf[s] = *(const s16x8*)(qrow + 16 * s + 8 * hh);

    f32x16 o0 = {}, o1 = {};                     // O^T: d 0..31 / 32..63
    float mrun = 0.f, lrun = 0.f;

    const int nt = 2 * qt + 2;                   // nt >= 2 always
    STAGE(0, 0);
    STAGE(1, 1);

    for (int t = 0; t < nt; ++t) {
      if (t + 2 < nt) {
        STAGE((t + 2) & 3, t + 2);
        asm volatile("s_waitcnt vmcnt(8)" ::: "memory");
      } else if (t + 2 == nt) {
        asm volatile("s_waitcnt vmcnt(4)" ::: "memory");
      } else {
        asm volatile("s_waitcnt vmcnt(0)" ::: "memory");
      }
      __builtin_amdgcn_s_barrier();              // all waves' tile-t stage done

      const int kv0 = t * 64;
      if (kv0 <= qt * 128 + w * 32 + 31) {       // wave-uniform active gate
        const u16* Kb = &Ks[t & 3][0];
        const u16* Vb = &Vs[t & 3][0];

        // ---- QK^T (S^T = K * Q^T): raw scores, two 32-kv halves
        f32x16 a0 = {}, a1 = {};
        __builtin_amdgcn_s_setprio(1);
#pragma unroll
        for (int s = 0; s < 4; ++s) {
          const int c0 = ((2 * s + hh) ^ xsw) * 8;
          s16x8 k0 = *(const s16x8*)(Kb + l31 * 64 + c0);
          s16x8 k1 = *(const s16x8*)(Kb + (32 + l31) * 64 + c0);
          a0 = mfma32(k0, qf[s], a0);
          a1 = mfma32(k1, qf[s], a1);
        }
        __builtin_amdgcn_s_setprio(0);

        // ---- causal mask (raw domain)
        if (kv0 + 63 > qt * 128 + w * 32) {
#pragma unroll
          for (int r = 0; r < 16; ++r) {
            const int kva = kv0 + (r & 3) + 8 * (r >> 2) + 4 * hh;
            if (kva > q_abs) a0[r] = -3e38f;
            if (kva + 32 > q_abs) a1[r] = -3e38f;
          }
        }

        // ---- max (raw), defer-max with THR=8 (log2 domain)
        float mxr = -3e38f;
#pragma unroll
        for (int r = 0; r < 16; ++r) mxr = fmaxf(mxr, fmaxf(a0[r], a1[r]));
        float mx = fmaxf(mxr * SCL, __shfl_xor(mxr * SCL, 32));
        const bool need = __any(mx > mrun + 8.f);
        float mnew = mrun, c1 = 1.f;
        if (need) {
          mnew = fmaxf(mrun, mx);
          c1 = fexp2(mrun - mnew);
        }

        // ---- exp2(raw*SCL - mnew) in place; row sum
        float sum = 0.f;
#pragma unroll
        for (int r = 0; r < 16; ++r) {
          a0[r] = fexp2(__builtin_fmaf(a0[r], SCL, -mnew));
          a1[r] = fexp2(__builtin_fmaf(a1[r], SCL, -mnew));
          sum += a0[r] + a1[r];
        }
        sum += __shfl_xor(sum, 32);
        lrun = lrun * c1 + sum;
        mrun = mnew;
        if (need) {
#pragma unroll
          for (int r = 0; r < 16; ++r) { o0[r] *= c1; o1[r] *= c1; }
        }

        // ---- pack P^T B-fragments (cvt_pk + permlane32_swap)
        s16x8 pf[4];
#pragma unroll
        for (int s = 0; s < 4; ++s) {
          const f32x16& ps = (s & 2) ? a1 : a0;
          const int g4 = (s & 1) * 8;
          u32 x  = cvtpk(ps[g4 + 0], ps[g4 + 1]);
          u32 x2 = cvtpk(ps[g4 + 2], ps[g4 + 3]);
          u32 y  = cvtpk(ps[g4 + 4], ps[g4 + 5]);
          u32 y2 = cvtpk(ps[g4 + 6], ps[g4 + 7]);
          asm("v_permlane32_swap_b32 %0, %1" : "+v"(x), "+v"(y));
          asm("v_permlane32_swap_b32 %0, %1" : "+v"(x2), "+v"(y2));
          u32x4 fr = {x, x2, y, y2};
          pf[s] = __builtin_bit_cast(s16x8, fr);
        }

        // ---- PV: O^T += V^T * P^T
        __builtin_amdgcn_s_setprio(1);
#pragma unroll
        for (int s = 0; s < 4; ++s) {
          const int c0 = ((2 * s + hh) ^ xsw) * 8;
          s16x8 v0f = *(const s16x8*)(Vb + l31 * 64 + c0);
          s16x8 v1f = *(const s16x8*)(Vb + (32 + l31) * 64 + c0);
          o0 = mfma32(v0f, pf[s], o0);
          o1 = mfma32(v1f, pf[s], o1);
        }
        __builtin_amdgcn_s_setprio(0);
      }
    }
    __syncthreads();                             // protect ring before reuse

    const float inv = 1.f / lrun;
    u16* ob = aout + (size_t)(b * 2048 + q_abs) * 2048 + h * 64;
#pragma unroll
    for (int g = 0; g < 4; ++g) {
      u16x4 w0, w1;
#pragma unroll
      for (int j = 0; j < 4; ++j) {
        w0[j] = f2bf(o0[4 * g + j] * inv);
        w1[j] = f2bf(o1[4 * g + j] * inv);
      }
      *(u16x4*)(ob + 8 * g + 4 * hh) = w0;
      *(u16x4*)(ob + 32 + 8 * g + 4 * hh) = w1;
    }
  };

  process(15 - bx);   // heavy q-tile
  process(bx);        // light q-tile -> constant 34 KV-tiles per block
}

// ---------------------------------------------------------------------------
extern "C" void kernel_launch(void* const* d_in, const int* in_sizes, int n_in,
                              void* d_out, int out_size, void* d_ws, size_t ws_size,
                              hipStream_t stream) {
  const float* x    = (const float*)d_in[0];
  const float* wq   = (const float*)d_in[1];
  const float* wk   = (const float*)d_in[2];
  const float* wv   = (const float*)d_in[3];
  const float* wo   = (const float*)d_in[4];
  const float* cosT = (const float*)d_in[5];
  const float* sinT = (const float*)d_in[6];
  float* out = (float*)d_out;

  const size_t SZ_XB   = (size_t)4096 * 2048 * 2;
  const size_t SZ_WQKV = (size_t)3072 * 2048 * 2;
  const size_t SZ_WO   = (size_t)2048 * 2048 * 2;
  const size_t SZ_QKV  = (size_t)4096 * 3072 * 2;
  const size_t SZ_ATT  = (size_t)4096 * 2048 * 2;
  if (ws_size < SZ_XB + SZ_WQKV + SZ_WO + SZ_QKV + SZ_ATT) return;

  char* p = (char*)d_ws;
  u16* xb    = (u16*)p; p += SZ_XB;
  u16* wqkvT = (u16*)p; p += SZ_WQKV;
  u16* woT   = (u16*)p; p += SZ_WO;
  u16* qkv   = (u16*)p; p += SZ_QKV;
  u16* attn  = (u16*)p; p += SZ_ATT;
  u16* VtG   = xb;   // xb is dead after the QKV GEMM; vt_kernel runs after it

  cvt_kernel<<<8192, 256, 0, stream>>>(x, xb, 2097152);
  tcvt_kernel<<<dim3(64, 64), 256, 0, stream>>>(wq, wqkvT, 2048);
  tcvt_kernel<<<dim3(16, 64), 256, 0, stream>>>(wk, wqkvT + (size_t)2048 * 2048, 512);
  tcvt_kernel<<<dim3(16, 64), 256, 0, stream>>>(wv, wqkvT + (size_t)2560 * 2048, 512);
  tcvt_kernel<<<dim3(64, 64), 256, 0, stream>>>(wo, woT, 2048);

  gemm256<<<192, 512, 0, stream>>>(xb, wqkvT, qkv, 4096, 3072, 2048, 12);
  rope_kernel<<<dim3(4096, 5), 256, 0, stream>>>(qkv, cosT, sinT);
  vt_kernel<<<dim3(32, 16), 256, 0, stream>>>(qkv, VtG);
  attn_kernel<<<dim3(8, 64), 256, 0, stream>>>(qkv, VtG, attn);
  gemm_bt<false><<<512, 256, 0, stream>>>(attn, woT, out, 4096, 2048, 2048, 16);
}

// Round 7
// 233.144 us; speedup vs baseline: 1.1013x; 1.0308x over previous
//
#include <hip/hip_runtime.h>

// ---------------------------------------------------------------------------
// Attention block (B=2, S=2048, DIM=2048, H=32, KVH=8, HD=64, causal, RoPE)
// cvt(x)->bf16 ; transpose-cvt weights ; QKV GEMM (256^2, BK=32, 4-buf ring,
// counted vmcnt) ; RoPE ; V-transpose ; balanced paired-q-tile flash
// attention ; out GEMM (128^2 2-phase) -> fp32 d_out
// ---------------------------------------------------------------------------

using u16   = unsigned short;
using u32   = unsigned int;
using f32x4 = __attribute__((ext_vector_type(4))) float;
using f32x16= __attribute__((ext_vector_type(16))) float;
using s16x8 = __attribute__((ext_vector_type(8))) short;
using b16x8 = __attribute__((ext_vector_type(8))) __bf16;
using u16x4 = __attribute__((ext_vector_type(4))) unsigned short;
using u32x4 = __attribute__((ext_vector_type(4))) u32;

__device__ __forceinline__ u16 f2bf(float f) {
  u32 u = __builtin_bit_cast(u32, f);
  u = (u + 0x7fffu + ((u >> 16) & 1u)) >> 16;   // round-to-nearest-even
  return (u16)u;
}
__device__ __forceinline__ float bf2f(u32 lo16) {
  return __builtin_bit_cast(float, lo16 << 16);
}

__device__ __forceinline__ f32x4 mfma16(s16x8 a, s16x8 b, f32x4 c) {
  return __builtin_amdgcn_mfma_f32_16x16x32_bf16(
      __builtin_bit_cast(b16x8, a), __builtin_bit_cast(b16x8, b), c, 0, 0, 0);
}
__device__ __forceinline__ f32x16 mfma32(s16x8 a, s16x8 b, f32x16 c) {
  return __builtin_amdgcn_mfma_f32_32x32x16_bf16(
      __builtin_bit_cast(b16x8, a), __builtin_bit_cast(b16x8, b), c, 0, 0, 0);
}

__device__ __forceinline__ void gload_lds16(const void* g, void* l) {
  __builtin_amdgcn_global_load_lds(
      (const __attribute__((address_space(1))) void*)g,
      (__attribute__((address_space(3))) void*)l, 16, 0, 0);
}

__device__ __forceinline__ u32 cvtpk(float lo, float hi) {
  u32 r; asm("v_cvt_pk_bf16_f32 %0, %1, %2" : "=v"(r) : "v"(lo), "v"(hi));
  return r;
}

__device__ __forceinline__ float fexp2(float x) {
#if __has_builtin(__builtin_amdgcn_exp2f)
  return __builtin_amdgcn_exp2f(x);
#else
  return exp2f(x);
#endif
}

// ---------------------------------------------------------------------------
__global__ __launch_bounds__(256) void cvt_kernel(const float* __restrict__ src,
                                                  u16* __restrict__ dst, int n4) {
  int i = blockIdx.x * 256 + threadIdx.x;
  if (i >= n4) return;
  f32x4 v = *(const f32x4*)(src + (size_t)i * 4);
  u16x4 r;
#pragma unroll
  for (int j = 0; j < 4; ++j) r[j] = f2bf(v[j]);
  *(u16x4*)(dst + (size_t)i * 4) = r;
}

// ---------------------------------------------------------------------------
__global__ __launch_bounds__(256) void tcvt_kernel(const float* __restrict__ src,
                                                   u16* __restrict__ dst, int N) {
  __shared__ float t[32][33];
  const int n0 = blockIdx.x * 32, k0 = blockIdx.y * 32;
  const int tx = threadIdx.x & 31, ty = threadIdx.x >> 5;
#pragma unroll
  for (int r = 0; r < 4; ++r)
    t[ty + 8 * r][tx] = src[(size_t)(k0 + ty + 8 * r) * N + n0 + tx];
  __syncthreads();
#pragma unroll
  for (int r = 0; r < 4; ++r)
    dst[(size_t)(n0 + ty + 8 * r) * 2048 + k0 + tx] = f2bf(t[tx][ty + 8 * r]);
}

// ---------------------------------------------------------------------------
__global__ __launch_bounds__(256) void rope_kernel(u16* __restrict__ qkv,
                                                   const float* __restrict__ cs,
                                                   const float* __restrict__ sn) {
  const int m = blockIdx.x;
  const int p = blockIdx.y * 256 + threadIdx.x;  // 0..1279
  const int s = m & 2047;
  int col, d2;
  if (p < 1024) { col = 2 * p; d2 = p & 31; }
  else { int pk = p - 1024; col = 2048 + 2 * pk; d2 = pk & 31; }
  const float c = cs[s * 32 + d2], si = sn[s * 32 + d2];
  u32* addr = (u32*)&qkv[(size_t)m * 3072 + col];
  u32 v = *addr;
  float a = bf2f(v & 0xffffu), b = bf2f(v >> 16);
  float na = a * c - b * si;
  float nb = a * si + b * c;
  *addr = (u32)f2bf(na) | ((u32)f2bf(nb) << 16);
}

// ---------------------------------------------------------------------------
// V transpose: qkv v-section -> VtG[(b*8+kvh)*64 + d][s]  ([16*64][2048] bf16)
__global__ __launch_bounds__(256) void vt_kernel(const u16* __restrict__ qkv,
                                                 u16* __restrict__ VtG) {
  __shared__ u16 t[64][65];
  const int s0 = blockIdx.x * 64;
  const int bk = blockIdx.y;            // b*8 + kvh
  const int b = bk >> 3, kvh = bk & 7;
  const int tx = threadIdx.x & 63, ty = threadIdx.x >> 6;  // ty 0..3
#pragma unroll
  for (int r = 0; r < 16; ++r)
    t[ty + 4 * r][tx] =
        qkv[(size_t)(b * 2048 + s0 + ty + 4 * r) * 3072 + 2560 + kvh * 64 + tx];
  __syncthreads();
#pragma unroll
  for (int r = 0; r < 16; ++r)
    VtG[(size_t)(bk * 64 + ty + 4 * r) * 2048 + s0 + tx] = t[tx][ty + 4 * r];
}

// ---------------------------------------------------------------------------
// 256x256 BK=32 8-wave GEMM (bf16 out): C[M,N] = A[M,K] * Bt[N,K]^T.
// Frag-major LDS (cell (frag,lane) = the 8 bf16 lane consumes for that
// 16x16x32 fragment -> ds_read_b128 at lane*16B, conflict-free; staging
// pre-permutes the GLOBAL source address, LDS writes stay linear).
// 4-buffer ring, prefetch distance 2 tiles, counted vmcnt(4) at boundaries
// (never drain to 0 mid-loop). 2 phases/tile, 16 MFMA each, setprio-wrapped.
__global__ __launch_bounds__(512, 2) void gemm256(const u16* __restrict__ A,
                                                  const u16* __restrict__ Bt,
                                                  u16* __restrict__ C,
                                                  int M, int N, int K, int GX) {
  __shared__ u16 As[4][16 * 512];   // [buf][frag][lane*8]  16 KB/buf
  __shared__ u16 Bs[4][16 * 512];
  const int tid = threadIdx.x;
  const int wv = tid >> 6, lane = tid & 63;
  const int l15 = lane & 15, lq = lane >> 4;
  const int wm = wv >> 2, wn = wv & 3;            // 2 x 4 wave grid
  const int cpx = gridDim.x >> 3;                 // grid % 8 == 0
  const int swz = (blockIdx.x & 7) * cpx + (blockIdx.x >> 3);
  const int m0 = (swz / GX) * 256, n0 = (swz % GX) * 256;

  // staging source per lane: row f*16+(lane&15), k-chunk 8*(lane>>4)
  const int sr = lane & 15, sk8 = 8 * (lane >> 4);

  auto STAGE_A = [&](int bb, int kt) {
#pragma unroll
    for (int i = 0; i < 2; ++i) {
      const int f = wv * 2 + i;                   // 0..15
      gload_lds16(A + (size_t)(m0 + f * 16 + sr) * K + kt + sk8,
                  &As[bb][f * 512]);
    }
  };
  auto STAGE_B = [&](int bb, int kt) {
#pragma unroll
    for (int i = 0; i < 2; ++i) {
      const int f = wv * 2 + i;
      gload_lds16(Bt + (size_t)(n0 + f * 16 + sr) * K + kt + sk8,
                  &Bs[bb][f * 512]);
    }
  };

  f32x4 acc[8][4] = {};
  STAGE_A(0, 0);  STAGE_B(0, 0);                  // tile 0 (4 loads)
  STAGE_A(1, 32); STAGE_B(1, 32);                 // tile 1 (4 loads)

  const int nt = K >> 5;                          // 64 tiles
  for (int t = 0; t < nt; ++t) {
    const int c = t & 3;
    // boundary: tile t's 4 loads are the oldest outstanding; tile t+1's 4
    // are the newest -> vmcnt(4) retires exactly tile t's. Last tile: 0.
    if (t + 1 < nt) asm volatile("s_waitcnt vmcnt(4)" ::: "memory");
    else            asm volatile("s_waitcnt vmcnt(0)" ::: "memory");
    __builtin_amdgcn_s_barrier();

    s16x8 a4[4], b4[4];
    // ---- phase 0: m-frags 0-3 x n-frags 0-3 (+ stage A of tile t+2)
#pragma unroll
    for (int i = 0; i < 4; ++i)
      a4[i] = *(const s16x8*)&As[c][(wm * 8 + i) * 512 + lane * 8];
#pragma unroll
    for (int j = 0; j < 4; ++j)
      b4[j] = *(const s16x8*)&Bs[c][(wn * 4 + j) * 512 + lane * 8];
    if (t + 2 < nt) STAGE_A((t + 2) & 3, (t + 2) << 5);
    __builtin_amdgcn_s_barrier();
    __builtin_amdgcn_s_setprio(1);
#pragma unroll
    for (int i = 0; i < 4; ++i)
#pragma unroll
      for (int j = 0; j < 4; ++j) acc[i][j] = mfma16(a4[i], b4[j], acc[i][j]);
    __builtin_amdgcn_s_setprio(0);
    __builtin_amdgcn_s_barrier();
    // ---- phase 1: m-frags 4-7 (b4 reused; + stage B of tile t+2)
#pragma unroll
    for (int i = 0; i < 4; ++i)
      a4[i] = *(const s16x8*)&As[c][(wm * 8 + 4 + i) * 512 + lane * 8];
    if (t + 2 < nt) STAGE_B((t + 2) & 3, (t + 2) << 5);
    __builtin_amdgcn_s_setprio(1);
#pragma unroll
    for (int i = 0; i < 4; ++i)
#pragma unroll
      for (int j = 0; j < 4; ++j)
        acc[4 + i][j] = mfma16(a4[i], b4[j], acc[4 + i][j]);
    __builtin_amdgcn_s_setprio(0);
    // next iteration's boundary barrier closes this phase
  }

#pragma unroll
  for (int i = 0; i < 8; ++i)
#pragma unroll
    for (int j = 0; j < 4; ++j)
#pragma unroll
      for (int r = 0; r < 4; ++r) {
        const int row = m0 + wm * 128 + i * 16 + 4 * lq + r;
        const int col = n0 + wn * 64 + j * 16 + l15;
        C[(size_t)row * N + col] = f2bf(acc[i][j][r]);
      }
}

// ---------------------------------------------------------------------------
// 128x128 BK=32 2-phase GEMM (fp32 out) for the output projection.
template <bool BF16OUT>
__global__ __launch_bounds__(256) void gemm_bt(const u16* __restrict__ A,
                                               const u16* __restrict__ Bt,
                                               void* __restrict__ Cv,
                                               int M, int N, int K, int GX) {
  __shared__ u16 As[2][128 * 32];
  __shared__ u16 Bs[2][128 * 32];
  const int tid = threadIdx.x;
  const int wid = tid >> 6, lane = tid & 63;
  const int l15 = lane & 15, lq = lane >> 4;
  const int wr = wid >> 1, wc = wid & 1;
  const int cpx = gridDim.x >> 3;                 // gridDim.x % 8 == 0
  const int swz = (blockIdx.x & 7) * cpx + (blockIdx.x >> 3);
  const int m0 = (swz / GX) * 128, n0 = (swz % GX) * 128;

  const int srow16 = lane >> 2;
  const int k8 = (lane & 3) * 8;

  auto STAGE = [&](int bb, int kt) {
#pragma unroll
    for (int i = 0; i < 2; ++i) {
      const int r = wid * 2 + i;                  // 16-row region
      const int row = r * 16 + srow16;
      gload_lds16(A + (size_t)(m0 + row) * K + kt + k8, &As[bb][r * 512]);
      gload_lds16(Bt + (size_t)(n0 + row) * K + kt + k8, &Bs[bb][r * 512]);
    }
  };

  f32x4 acc[4][4] = {};
  STAGE(0, 0);
  __syncthreads();
  int cur = 0;
  for (int kt = 0; kt < K; kt += 32) {
    if (kt + 32 < K) STAGE(cur ^ 1, kt + 32);
    s16x8 af[4], bf[4];
#pragma unroll
    for (int i = 0; i < 4; ++i)
      af[i] = *(const s16x8*)&As[cur][(wr * 64 + i * 16 + l15) * 32 + 8 * lq];
#pragma unroll
    for (int j = 0; j < 4; ++j)
      bf[j] = *(const s16x8*)&Bs[cur][(wc * 64 + j * 16 + l15) * 32 + 8 * lq];
#pragma unroll
    for (int i = 0; i < 4; ++i)
#pragma unroll
      for (int j = 0; j < 4; ++j)
        acc[i][j] = mfma16(af[i], bf[j], acc[i][j]);
    __syncthreads();                              // drains next-tile loads too
    cur ^= 1;
  }

  u16* Cb = (u16*)Cv;
  float* Cf = (float*)Cv;
#pragma unroll
  for (int i = 0; i < 4; ++i)
#pragma unroll
    for (int j = 0; j < 4; ++j)
#pragma unroll
      for (int r = 0; r < 4; ++r) {
        const int row = m0 + wr * 64 + i * 16 + 4 * lq + r;
        const int col = n0 + wc * 64 + j * 16 + l15;
        if constexpr (BF16OUT) Cb[(size_t)row * N + col] = f2bf(acc[i][j][r]);
        else                   Cf[(size_t)row * N + col] = acc[i][j][r];
      }
}

// ---------------------------------------------------------------------------
// Flash attention (round-4 version): balanced pairs + 4-deep LDS ring with
// counted-vmcnt prefetch (2 tiles ahead). 4 waves x 32 q-rows (QBLK=128),
// KVBLK=64. Block bx does q-tiles {15-bx, bx} -> constant 34 KV-tiles/block.
// Swapped QK^T (S^T) + O^T: softmax lane-local. Defer-max THR=8 (log2).
__global__ __launch_bounds__(256) void attn_kernel(const u16* __restrict__ qkv,
                                                   const u16* __restrict__ VtG,
                                                   u16* __restrict__ aout) {
  constexpr int QSTR = 3072;
  constexpr float SCL = 0.18033688011112042f;    // (1/8) * log2(e)
  const int bx = blockIdx.x;                     // 0..7
  const int bh = blockIdx.y;
  const int b = bh >> 5, h = bh & 31, kvh = h >> 2;
  const int tid = threadIdx.x, w = tid >> 6;     // wave 0..3
  const int l31 = tid & 31, hh = (tid >> 5) & 1;

  __shared__ u16 Ks[4][64 * 64];
  __shared__ u16 Vs[4][64 * 64];

  const int srow = tid >> 3, sslot = tid & 7;
  const int sd8 = (sslot ^ (srow & 7)) * 8;      // pre-swizzled source slot
  const u16* kg = qkv + (size_t)(b * 2048 + srow) * QSTR + 2048 + kvh * 64 + sd8;
  const u16* vg = VtG + (size_t)((b * 8 + kvh) * 64 + srow) * 2048 + sd8;
  const int xsw = l31 & 7;                       // read-side row XOR

  auto STAGE = [&](int bb, int t) {
    const size_t ko = (size_t)t * 64 * QSTR;
    const size_t vo = (size_t)t * 64;
    gload_lds16(kg + ko, &Ks[bb][w * 512]);
    gload_lds16(kg + ko + (size_t)32 * QSTR, &Ks[bb][2048 + w * 512]);
    gload_lds16(vg + vo, &Vs[bb][w * 512]);
    gload_lds16(vg + vo + (size_t)32 * 2048, &Vs[bb][2048 + w * 512]);
  };

  auto process = [&](int qt) {
    const int q_abs = qt * 128 + w * 32 + l31;   // this lane's q row
    const u16* qrow = qkv + (size_t)(b * 2048 + q_abs) * QSTR + h * 64;
    s16x8 qf[4];
#pragma unroll
    for (int s = 0; s < 4; ++s) qf[s] = *(const s16x8*)(qrow + 16 * s + 8 * hh);

    f32x16 o0 = {}, o1 = {};                     // O^T: d 0..31 / 32..63
    float mrun = 0.f, lrun = 0.f;

    const int nt = 2 * qt + 2;                   // nt >= 2 always
    STAGE(0, 0);
    STAGE(1, 1);

    for (int t = 0; t < nt; ++t) {
      if (t + 2 < nt) {
        STAGE((t + 2) & 3, t + 2);
        asm volatile("s_waitcnt vmcnt(8)" ::: "memory");
      } else if (t + 2 == nt) {
        asm volatile("s_waitcnt vmcnt(4)" ::: "memory");
      } else {
        asm volatile("s_waitcnt vmcnt(0)" ::: "memory");
      }
      __builtin_amdgcn_s_barrier();              // all waves' tile-t stage done

      const int kv0 = t * 64;
      if (kv0 <= qt * 128 + w * 32 + 31) {       // wave-uniform active gate
        const u16* Kb = &Ks[t & 3][0];
        const u16* Vb = &Vs[t & 3][0];

        // ---- QK^T (S^T = K * Q^T): raw scores, two 32-kv halves
        f32x16 a0 = {}, a1 = {};
        __builtin_amdgcn_s_setprio(1);
#pragma unroll
        for (int s = 0; s < 4; ++s) {
          const int c0 = ((2 * s + hh) ^ xsw) * 8;
          s16x8 k0 = *(const s16x8*)(Kb + l31 * 64 + c0);
          s16x8 k1 = *(const s16x8*)(Kb + (32 + l31) * 64 + c0);
          a0 = mfma32(k0, qf[s], a0);
          a1 = mfma32(k1, qf[s], a1);
        }
        __builtin_amdgcn_s_setprio(0);

        // ---- causal mask (raw domain)
        if (kv0 + 63 > qt * 128 + w * 32) {
#pragma unroll
          for (int r = 0; r < 16; ++r) {
            const int kva = kv0 + (r & 3) + 8 * (r >> 2) + 4 * hh;
            if (kva > q_abs) a0[r] = -3e38f;
            if (kva + 32 > q_abs) a1[r] = -3e38f;
          }
        }

        // ---- max (raw), defer-max with THR=8 (log2 domain)
        float mxr = -3e38f;
#pragma unroll
        for (int r = 0; r < 16; ++r) mxr = fmaxf(mxr, fmaxf(a0[r], a1[r]));
        float mx = fmaxf(mxr * SCL, __shfl_xor(mxr * SCL, 32));
        const bool need = __any(mx > mrun + 8.f);
        float mnew = mrun, c1 = 1.f;
        if (need) {
          mnew = fmaxf(mrun, mx);
          c1 = fexp2(mrun - mnew);
        }

        // ---- exp2(raw*SCL - mnew) in place; row sum
        float sum = 0.f;
#pragma unroll
        for (int r = 0; r < 16; ++r) {
          a0[r] = fexp2(__builtin_fmaf(a0[r], SCL, -mnew));
          a1[r] = fexp2(__builtin_fmaf(a1[r], SCL, -mnew));
          sum += a0[r] + a1[r];
        }
        sum += __shfl_xor(sum, 32);
        lrun = lrun * c1 + sum;
        mrun = mnew;
        if (need) {
#pragma unroll
          for (int r = 0; r < 16; ++r) { o0[r] *= c1; o1[r] *= c1; }
        }

        // ---- pack P^T B-fragments (cvt_pk + permlane32_swap)
        s16x8 pf[4];
#pragma unroll
        for (int s = 0; s < 4; ++s) {
          const f32x16& ps = (s & 2) ? a1 : a0;
          const int g4 = (s & 1) * 8;
          u32 x  = cvtpk(ps[g4 + 0], ps[g4 + 1]);
          u32 x2 = cvtpk(ps[g4 + 2], ps[g4 + 3]);
          u32 y  = cvtpk(ps[g4 + 4], ps[g4 + 5]);
          u32 y2 = cvtpk(ps[g4 + 6], ps[g4 + 7]);
          asm("v_permlane32_swap_b32 %0, %1" : "+v"(x), "+v"(y));
          asm("v_permlane32_swap_b32 %0, %1" : "+v"(x2), "+v"(y2));
          u32x4 fr = {x, x2, y, y2};
          pf[s] = __builtin_bit_cast(s16x8, fr);
        }

        // ---- PV: O^T += V^T * P^T
        __builtin_amdgcn_s_setprio(1);
#pragma unroll
        for (int s = 0; s < 4; ++s) {
          const int c0 = ((2 * s + hh) ^ xsw) * 8;
          s16x8 v0f = *(const s16x8*)(Vb + l31 * 64 + c0);
          s16x8 v1f = *(const s16x8*)(Vb + (32 + l31) * 64 + c0);
          o0 = mfma32(v0f, pf[s], o0);
          o1 = mfma32(v1f, pf[s], o1);
        }
        __builtin_amdgcn_s_setprio(0);
      }
    }
    __syncthreads();                             // protect ring before reuse

    const float inv = 1.f / lrun;
    u16* ob = aout + (size_t)(b * 2048 + q_abs) * 2048 + h * 64;
#pragma unroll
    for (int g = 0; g < 4; ++g) {
      u16x4 w0, w1;
#pragma unroll
      for (int j = 0; j < 4; ++j) {
        w0[j] = f2bf(o0[4 * g + j] * inv);
        w1[j] = f2bf(o1[4 * g + j] * inv);
      }
      *(u16x4*)(ob + 8 * g + 4 * hh) = w0;
      *(u16x4*)(ob + 32 + 8 * g + 4 * hh) = w1;
    }
  };

  process(15 - bx);   // heavy q-tile
  process(bx);        // light q-tile -> constant 34 KV-tiles per block
}

// ---------------------------------------------------------------------------
extern "C" void kernel_launch(void* const* d_in, const int* in_sizes, int n_in,
                              void* d_out, int out_size, void* d_ws, size_t ws_size,
                              hipStream_t stream) {
  const float* x    = (const float*)d_in[0];
  const float* wq   = (const float*)d_in[1];
  const float* wk   = (const float*)d_in[2];
  const float* wv   = (const float*)d_in[3];
  const float* wo   = (const float*)d_in[4];
  const float* cosT = (const float*)d_in[5];
  const float* sinT = (const float*)d_in[6];
  float* out = (float*)d_out;

  const size_t SZ_XB   = (size_t)4096 * 2048 * 2;
  const size_t SZ_WQKV = (size_t)3072 * 2048 * 2;
  const size_t SZ_WO   = (size_t)2048 * 2048 * 2;
  const size_t SZ_QKV  = (size_t)4096 * 3072 * 2;
  const size_t SZ_ATT  = (size_t)4096 * 2048 * 2;
  if (ws_size < SZ_XB + SZ_WQKV + SZ_WO + SZ_QKV + SZ_ATT) return;

  char* p = (char*)d_ws;
  u16* xb    = (u16*)p; p += SZ_XB;
  u16* wqkvT = (u16*)p; p += SZ_WQKV;
  u16* woT   = (u16*)p; p += SZ_WO;
  u16* qkv   = (u16*)p; p += SZ_QKV;
  u16* attn  = (u16*)p; p += SZ_ATT;
  u16* VtG   = xb;   // xb is dead after the QKV GEMM; vt_kernel runs after it

  cvt_kernel<<<8192, 256, 0, stream>>>(x, xb, 2097152);
  tcvt_kernel<<<dim3(64, 64), 256, 0, stream>>>(wq, wqkvT, 2048);
  tcvt_kernel<<<dim3(16, 64), 256, 0, stream>>>(wk, wqkvT + (size_t)2048 * 2048, 512);
  tcvt_kernel<<<dim3(16, 64), 256, 0, stream>>>(wv, wqkvT + (size_t)2560 * 2048, 512);
  tcvt_kernel<<<dim3(64, 64), 256, 0, stream>>>(wo, woT, 2048);

  gemm256<<<192, 512, 0, stream>>>(xb, wqkvT, qkv, 4096, 3072, 2048, 12);
  rope_kernel<<<dim3(4096, 5), 256, 0, stream>>>(qkv, cosT, sinT);
  vt_kernel<<<dim3(32, 16), 256, 0, stream>>>(qkv, VtG);
  attn_kernel<<<dim3(8, 64), 256, 0, stream>>>(qkv, VtG, attn);
  gemm_bt<false><<<512, 256, 0, stream>>>(attn, woT, out, 4096, 2048, 2048, 16);
}